// Round 11
// baseline (86.878 us; speedup 1.0000x reference)
//
#include <hip/hip_runtime.h>
#include <math.h>

#define BB 8
#define TT 200
#define UU 50          // label positions; alpha lattice has U1 = 51 columns
#define VV 1024
#define U1 (UU + 1)
#define NROWS (BB * TT * U1)   // 81600 softmax rows
#define RPW 4                  // rows per wave, LDS double-buffered

#define LOG2E 1.44269504088896340736f
#define LN2   0.69314718055994530942f

// DPP wave_shr:1 — lane i gets lane i-1's value, lane 0 gets 0.
__device__ __forceinline__ float wave_shr1(float x) {
    int xi = __builtin_bit_cast(int, x);
    int r  = __builtin_amdgcn_update_dpp(0, xi, 0x138, 0xF, 0xF, true);
    return __builtin_bit_cast(float, r);
}

// ---------------- Kernel 1: row-wise logZ via LDS-prefetch pipeline -------------
// Each wave owns RPW rows and two 4KB LDS slots. Per iteration: issue row k+1's
// 4 global_load_lds (VGPR-free prefetch), then s_waitcnt vmcnt(4) — FIFO drain
// completes row k's loads (and all older stores) while row k+1 stays in
// flight. sched_barrier(0) pins exactly 4 VMEM ops in the window. No
// __syncthreads needed: each wave touches only its own slots.
__global__ __launch_bounds__(256) void k_logp(const float* __restrict__ acts,
                                              const int* __restrict__ labels,
                                              float* __restrict__ lpb,
                                              float* __restrict__ lpe,
                                              float* __restrict__ out) {
    if (blockIdx.x == 0 && threadIdx.x == 0) out[0] = 0.0f;
    __shared__ __align__(16) float s_buf[4 * 2 * VV];   // 4 waves x 2 slots x 4KB
    const int wave = threadIdx.x >> 6;
    const int lane = threadIdx.x & 63;
    const int row0 = (blockIdx.x * 4 + wave) * RPW;     // grid*16 == NROWS
    float* sl[2] = { &s_buf[wave * 2 * VV], &s_buf[wave * 2 * VV + VV] };

    // prologue: per-row metadata + label loads (drained by first vmcnt(4))
    int labA[RPW], uA[RPW], idxA[RPW];
#pragma unroll
    for (int k = 0; k < RPW; ++k) {
        int r = row0 + k;
        int b = r / (TT * U1), rem = r - b * (TT * U1);
        int t = rem / U1, u = rem - t * U1;
        uA[k]   = u;
        labA[k] = (u < UU) ? labels[b * UU + u] : 0;
        idxA[k] = (b * TT + t) * UU + u;
    }

    // issue row0 -> slot0
    {
        const float* g = acts + (size_t)row0 * VV;
        __builtin_amdgcn_sched_barrier(0);
#pragma unroll
        for (int c = 0; c < 4; ++c)
            __builtin_amdgcn_global_load_lds(g + c * 256 + lane * 4, sl[0] + c * 256, 16, 0, 0);
        __builtin_amdgcn_sched_barrier(0);
    }

#pragma unroll
    for (int k = 0; k < RPW; ++k) {
        const int row = row0 + k;
        float* cur = sl[k & 1];
        if (k < RPW - 1) {
            const float* g = acts + (size_t)(row + 1) * VV;
            float* nxt = sl[(k + 1) & 1];
            __builtin_amdgcn_sched_barrier(0);
#pragma unroll
            for (int c = 0; c < 4; ++c)
                __builtin_amdgcn_global_load_lds(g + c * 256 + lane * 4, nxt + c * 256, 16, 0, 0);
            __builtin_amdgcn_sched_barrier(0);
            asm volatile("s_waitcnt vmcnt(4)" ::: "memory");   // row k done, k+1 in flight
        } else {
            asm volatile("s_waitcnt vmcnt(0)" ::: "memory");
        }

        float4 v0 = *(const float4*)(cur + 0 * 256 + lane * 4);
        float4 v1 = *(const float4*)(cur + 1 * 256 + lane * 4);
        float4 v2 = *(const float4*)(cur + 2 * 256 + lane * 4);
        float4 v3 = *(const float4*)(cur + 3 * 256 + lane * 4);

        const int lab = labA[k];
        const int cidx = lab >> 8, lidx = (lab >> 2) & 63, eidx = lab & 3;
        float alab = 0.0f;

        float sum = __expf(v0.x) + __expf(v0.y) + __expf(v0.z) + __expf(v0.w);
        if (cidx == 0) alab = (eidx & 2) ? ((eidx & 1) ? v0.w : v0.z) : ((eidx & 1) ? v0.y : v0.x);
        sum += __expf(v1.x) + __expf(v1.y) + __expf(v1.z) + __expf(v1.w);
        if (cidx == 1) alab = (eidx & 2) ? ((eidx & 1) ? v1.w : v1.z) : ((eidx & 1) ? v1.y : v1.x);
        sum += __expf(v2.x) + __expf(v2.y) + __expf(v2.z) + __expf(v2.w);
        if (cidx == 2) alab = (eidx & 2) ? ((eidx & 1) ? v2.w : v2.z) : ((eidx & 1) ? v2.y : v2.x);
        sum += __expf(v3.x) + __expf(v3.y) + __expf(v3.z) + __expf(v3.w);
        if (cidx == 3) alab = (eidx & 2) ? ((eidx & 1) ? v3.w : v3.z) : ((eidx & 1) ? v3.y : v3.x);

#pragma unroll
        for (int s = 1; s < 64; s <<= 1) sum += __shfl_xor(sum, s, 64);
        float logZ = __logf(sum);

        if (uA[k] < UU && lane == lidx) lpe[idxA[k]] = alab - logZ;
        if (lane == 0)                  lpb[row]    = v0.x - logZ;
    }
}

// ---------------- Kernel 2: anti-diagonal DP + one atomicAdd per block ----------
// One block per batch. 256 threads stage lpb/lpe (base-2 scaled) into LDS,
// wave 0 walks diagonals 1..dtgt (early exit past the answer cell), one lane
// atomicAdds -loglike into out[0].
__global__ __launch_bounds__(256) void k_dp(const float* __restrict__ lpb,
                                            const float* __restrict__ lpe,
                                            const int* __restrict__ act_lens,
                                            const int* __restrict__ label_lens,
                                            float* __restrict__ out) {
    __shared__ __align__(16) float s_lpb[TT * U1];   // 40.8 KB
    __shared__ __align__(16) float s_lpe[TT * UU];   // 40.0 KB

    const int b = blockIdx.x;
    const float4* gb4 = (const float4*)(lpb + (size_t)b * TT * U1);
    const float4* ge4 = (const float4*)(lpe + (size_t)b * TT * UU);
    float4* sb4 = (float4*)s_lpb;
    float4* se4 = (float4*)s_lpe;
    for (int i = threadIdx.x; i < TT * U1 / 4; i += 256) {
        float4 v = gb4[i];
        v.x *= LOG2E; v.y *= LOG2E; v.z *= LOG2E; v.w *= LOG2E;
        sb4[i] = v;
    }
    for (int i = threadIdx.x; i < TT * UU / 4; i += 256) {
        float4 v = ge4[i];
        v.x *= LOG2E; v.y *= LOG2E; v.z *= LOG2E; v.w *= LOG2E;
        se4[i] = v;
    }
    __syncthreads();
    if (threadIdx.x >= 64) return;

    const int u  = threadIdx.x;        // lane == u; lanes 51..63 carry -inf
    const int uc = min(u, UU);
    const int tl = act_lens[b] - 1;
    const int ul = label_lens[b];
    const int dtgt = tl + ul;          // block-uniform: loop only this far
    const float NEG = -INFINITY;
    const float bsave = s_lpb[tl * U1 + ul];

    float Aprev = (u == 0) ? 0.0f : NEG;
    float saved = (dtgt == 0 && u == 0) ? bsave : NEG;

#pragma unroll 5
    for (int d = 1; d <= dtgt; ++d) {
        float Aup = wave_shr1(Aprev);
        int t  = d - u;
        int tb = min(max(t - 1, 0), TT - 1);
        int te = min(max(t, 0), TT - 1);
        float bv = s_lpb[tb * U1 + uc];
        float ev = s_lpe[te * UU + max(uc - 1, 0)];
        bool cellok = (t >= 0) & (t < TT) & (u <= UU);
        float ft = (cellok & (t >= 1)) ? Aprev + bv : NEG;
        float em = (cellok & (u >= 1)) ? Aup + ev   : NEG;
        float mm = fmaxf(ft, em);
        float dd = fminf(ft, em) - mm;
        float A  = mm + __builtin_amdgcn_logf(1.0f + __builtin_amdgcn_exp2f(dd));
        A = cellok ? A : NEG;
        saved = (d == dtgt && u == ul) ? A + bsave : saved;
        Aprev = A;
    }
    if (u == ul) atomicAdd(out, -(saved * LN2));
}

extern "C" void kernel_launch(void* const* d_in, const int* in_sizes, int n_in,
                              void* d_out, int out_size, void* d_ws, size_t ws_size,
                              hipStream_t stream) {
    const float* acts       = (const float*)d_in[0];
    const int*   labels     = (const int*)d_in[1];
    const int*   act_lens   = (const int*)d_in[2];
    const int*   label_lens = (const int*)d_in[3];

    float* ws  = (float*)d_ws;
    float* lpb = ws;                         // B*T*U1  = 81600 floats
    float* lpe = lpb + NROWS;                // B*T*U   = 80000 floats
    float* out = (float*)d_out;

    k_logp<<<NROWS / (4 * RPW), 256, 0, stream>>>(acts, labels, lpb, lpe, out);
    k_dp<<<BB, 256, 0, stream>>>(lpb, lpe, act_lens, label_lens, out);
}

// Round 12
// 78.113 us; speedup vs baseline: 1.1122x; 1.1122x over previous
//
#include <hip/hip_runtime.h>
#include <math.h>

#define BB 8
#define TT 200
#define UU 50          // label positions; alpha lattice has U1 = 51 columns
#define VV 1024
#define U1 (UU + 1)
#define NROWS (BB * TT * U1)   // 81600 softmax rows

#define LOG2E 1.44269504088896340736f
#define LN2   0.69314718055994530942f

typedef float f4v __attribute__((ext_vector_type(4)));   // nontemporal-compatible

// DPP wave_shr:1 — lane i gets lane i-1's value, lane 0 gets 0.
__device__ __forceinline__ float wave_shr1(float x) {
    int xi = __builtin_bit_cast(int, x);
    int r  = __builtin_amdgcn_update_dpp(0, xi, 0x138, 0xF, 0xF, true);
    return __builtin_bit_cast(float, r);
}

__device__ __forceinline__ float pickq(f4v v0, f4v v1, f4v v2, f4v v3, int lab) {
    int cidx = lab >> 8, eidx = lab & 3;
    f4v vs = (cidx == 0) ? v0 : (cidx == 1) ? v1 : (cidx == 2) ? v2 : v3;
    return (eidx & 2) ? ((eidx & 1) ? vs.w : vs.z) : ((eidx & 1) ? vs.y : vs.x);
}

// ---------------- Kernel 1: row-wise logZ; emit only lp_blank & lp_emit ---------
// TWO rows per wave, all 8 nontemporal float4 loads issued back-to-back
// (8 KB/wave in flight — 2x R10), two independent exp/reduce chains for VALU
// ILP. __launch_bounds__(256,8) pins VGPR <= 64 so occupancy stays at
// 8 waves/SIMD (TLP is this kernel's BW source — R8/R11 lesson).
__global__ __launch_bounds__(256, 8) void k_logp(const float* __restrict__ acts,
                                                 const int* __restrict__ labels,
                                                 float* __restrict__ lpb,
                                                 float* __restrict__ lpe,
                                                 float* __restrict__ out) {
    if (blockIdx.x == 0 && threadIdx.x == 0) out[0] = 0.0f;
    const int wave = threadIdx.x >> 6;
    const int lane = threadIdx.x & 63;
    const int r0   = (blockIdx.x * 4 + wave) * 2;    // grid*8 == NROWS
    const int r1   = r0 + 1;

    const f4v* p0 = (const f4v*)(acts + (size_t)r0 * VV);
    const f4v* p1 = (const f4v*)(acts + (size_t)r1 * VV);
    f4v a0 = __builtin_nontemporal_load(p0 + lane);
    f4v a1 = __builtin_nontemporal_load(p0 + 64 + lane);
    f4v a2 = __builtin_nontemporal_load(p0 + 128 + lane);
    f4v a3 = __builtin_nontemporal_load(p0 + 192 + lane);
    f4v c0 = __builtin_nontemporal_load(p1 + lane);
    f4v c1 = __builtin_nontemporal_load(p1 + 64 + lane);
    f4v c2 = __builtin_nontemporal_load(p1 + 128 + lane);
    f4v c3 = __builtin_nontemporal_load(p1 + 192 + lane);

    // metadata (r1 = r0+1 is in the same t-row or wraps; compute independently)
    int b0 = r0 / (TT * U1); int rem0 = r0 - b0 * (TT * U1);
    int t0 = rem0 / U1;      int u0   = rem0 - t0 * U1;
    int b1 = r1 / (TT * U1); int rem1 = r1 - b1 * (TT * U1);
    int t1 = rem1 / U1;      int u1   = rem1 - t1 * U1;
    int lab0 = (u0 < UU) ? labels[b0 * UU + u0] : 0;
    int lab1 = (u1 < UU) ? labels[b1 * UU + u1] : 0;

    // two independent exp/reduce chains (interleaved by the scheduler)
    float s0 = __expf(a0.x) + __expf(a0.y) + __expf(a0.z) + __expf(a0.w)
             + __expf(a1.x) + __expf(a1.y) + __expf(a1.z) + __expf(a1.w)
             + __expf(a2.x) + __expf(a2.y) + __expf(a2.z) + __expf(a2.w)
             + __expf(a3.x) + __expf(a3.y) + __expf(a3.z) + __expf(a3.w);
    float s1 = __expf(c0.x) + __expf(c0.y) + __expf(c0.z) + __expf(c0.w)
             + __expf(c1.x) + __expf(c1.y) + __expf(c1.z) + __expf(c1.w)
             + __expf(c2.x) + __expf(c2.y) + __expf(c2.z) + __expf(c2.w)
             + __expf(c3.x) + __expf(c3.y) + __expf(c3.z) + __expf(c3.w);
#pragma unroll
    for (int s = 1; s < 64; s <<= 1) { s0 += __shfl_xor(s0, s, 64); s1 += __shfl_xor(s1, s, 64); }

    float z0 = __logf(s0);
    float z1 = __logf(s1);

    int l0 = (lab0 >> 2) & 63, l1 = (lab1 >> 2) & 63;
    if (u0 < UU && lane == l0) lpe[(b0 * TT + t0) * UU + u0] = pickq(a0,a1,a2,a3,lab0) - z0;
    if (u1 < UU && lane == l1) lpe[(b1 * TT + t1) * UU + u1] = pickq(c0,c1,c2,c3,lab1) - z1;
    if (lane == 0) { lpb[r0] = a0.x - z0; lpb[r1] = c0.x - z1; }
}

// ---------------- Kernel 2: anti-diagonal DP + one atomicAdd per block ----------
// One block per batch. 256 threads stage lpb/lpe (base-2 scaled) into LDS,
// wave 0 walks diagonals 1..dtgt (early exit past the answer cell), one lane
// atomicAdds -loglike into out[0] (zeroed by k_logp earlier in the stream).
__global__ __launch_bounds__(256) void k_dp(const float* __restrict__ lpb,
                                            const float* __restrict__ lpe,
                                            const int* __restrict__ act_lens,
                                            const int* __restrict__ label_lens,
                                            float* __restrict__ out) {
    __shared__ __align__(16) float s_lpb[TT * U1];   // 40.8 KB
    __shared__ __align__(16) float s_lpe[TT * UU];   // 40.0 KB

    const int b = blockIdx.x;
    const float4* gb4 = (const float4*)(lpb + (size_t)b * TT * U1);
    const float4* ge4 = (const float4*)(lpe + (size_t)b * TT * UU);
    float4* sb4 = (float4*)s_lpb;
    float4* se4 = (float4*)s_lpe;
    for (int i = threadIdx.x; i < TT * U1 / 4; i += 256) {
        float4 v = gb4[i];
        v.x *= LOG2E; v.y *= LOG2E; v.z *= LOG2E; v.w *= LOG2E;
        sb4[i] = v;
    }
    for (int i = threadIdx.x; i < TT * UU / 4; i += 256) {
        float4 v = ge4[i];
        v.x *= LOG2E; v.y *= LOG2E; v.z *= LOG2E; v.w *= LOG2E;
        se4[i] = v;
    }
    __syncthreads();
    if (threadIdx.x >= 64) return;

    const int u  = threadIdx.x;        // lane == u; lanes 51..63 carry -inf
    const int uc = min(u, UU);
    const int tl = act_lens[b] - 1;
    const int ul = label_lens[b];
    const int dtgt = tl + ul;          // block-uniform: loop only this far
    const float NEG = -INFINITY;
    const float bsave = s_lpb[tl * U1 + ul];

    float Aprev = (u == 0) ? 0.0f : NEG;
    float saved = (dtgt == 0 && u == 0) ? bsave : NEG;

#pragma unroll 5
    for (int d = 1; d <= dtgt; ++d) {
        float Aup = wave_shr1(Aprev);
        int t  = d - u;
        int tb = min(max(t - 1, 0), TT - 1);
        int te = min(max(t, 0), TT - 1);
        float bv = s_lpb[tb * U1 + uc];
        float ev = s_lpe[te * UU + max(uc - 1, 0)];
        bool cellok = (t >= 0) & (t < TT) & (u <= UU);
        float ft = (cellok & (t >= 1)) ? Aprev + bv : NEG;
        float em = (cellok & (u >= 1)) ? Aup + ev   : NEG;
        float mm = fmaxf(ft, em);
        float dd = fminf(ft, em) - mm;
        float A  = mm + __builtin_amdgcn_logf(1.0f + __builtin_amdgcn_exp2f(dd));
        A = cellok ? A : NEG;
        saved = (d == dtgt && u == ul) ? A + bsave : saved;
        Aprev = A;
    }
    if (u == ul) atomicAdd(out, -(saved * LN2));
}

extern "C" void kernel_launch(void* const* d_in, const int* in_sizes, int n_in,
                              void* d_out, int out_size, void* d_ws, size_t ws_size,
                              hipStream_t stream) {
    const float* acts       = (const float*)d_in[0];
    const int*   labels     = (const int*)d_in[1];
    const int*   act_lens   = (const int*)d_in[2];
    const int*   label_lens = (const int*)d_in[3];

    float* ws  = (float*)d_ws;
    float* lpb = ws;                         // B*T*U1  = 81600 floats
    float* lpe = lpb + NROWS;                // B*T*U   = 80000 floats
    float* out = (float*)d_out;

    k_logp<<<NROWS / 8, 256, 0, stream>>>(acts, labels, lpb, lpe, out);
    k_dp<<<BB, 256, 0, stream>>>(lpb, lpe, act_lens, label_lens, out);
}